// Round 6
// baseline (206.248 us; speedup 1.0000x reference)
//
#include <hip/hip_runtime.h>

typedef __attribute__((ext_vector_type(8))) short short8;   // 8 x bf16 (4 VGPR)
typedef __attribute__((ext_vector_type(4))) float f32x4;

#define Bsz 4
#define Cin 256
#define Cout 256
#define Hh 64
#define Ww 64
#define HW 4096
#define NG 16
#define EPSV 1e-5f

#define CSTR 40        // col LDS row stride in ushorts: 32 data + 8 pad = 80 B
#define SPAN 12        // staged input rows per window
#define ROWB 4112      // staged row stride bytes: 16 pairs x 64 px x 4B + 16 pad

// ---- dcn dynamic LDS layout (bytes) ----
#define OFF_IN   0
#define SZ_IN    (SPAN * ROWB)         // 49344: bf16 pair-plane window
#define OFF_COL  49344                 // 2 x 32 x CSTR ushorts = 5120
#define OFF_TA   54464                 // int2 per tap [9][32] = 2304
#define OFF_TW   56768                 // float4 per tap [9][32] = 4608
#define OFF_CTL  61376                 // ymin/ymax
#define SMEM_BYTES 61392               // x2 blocks = 122784 <= 160 KiB/CU

static __device__ __forceinline__ unsigned f2bf(float f) {
    unsigned u = __float_as_uint(f);
    return (u + 0x7fffu + ((u >> 16) & 1u)) >> 16;   // RNE bf16
}

static __device__ __forceinline__ float2 ld8(const float* p) {
    float2 v;
    __builtin_memcpy(&v, p, 8);   // 8B load (global or LDS)
    return v;
}

#define BLO(u) __uint_as_float((u) << 16)          // bf16 in low half -> f32
#define BHI(u) __uint_as_float((u) & 0xffff0000u)  // bf16 in high half -> f32

// ---------------------------------------------------------------------------
// Kernel 1 (fused prep):
//  blocks [0,256): input transpose NCHW f32 -> bf16 pair-plane
//      inT word(u32 = ch2p lo | ch2p+1 hi) idx = ((b*64+y)*128 + pr)*64 + x
//  blocks [256,1408): weight reorder w[o][c][kk] -> bf16 wtb[ks][o][32],
//      ks = kk*8 + c/32;  + zero GN stats accumulators.
// ---------------------------------------------------------------------------
__launch_bounds__(512)
__global__ void prep_kernel(const float* __restrict__ in,
                            const float* __restrict__ w,
                            unsigned* __restrict__ inT,
                            ushort* __restrict__ wtb,
                            float* __restrict__ stats) {
    const int t  = threadIdx.x;
    const int bx = blockIdx.x;
    if (bx < 256) {                    // ---- transpose ----
        const int b = bx >> 6, y = bx & 63;
        const int x = t & 63, w8 = t >> 6;
        const float* src = in + (size_t)b * 256 * HW + y * 64 + x;
        unsigned* dst = inT + ((size_t)(b * 64 + y) * 128) * 64 + x;
#pragma unroll
        for (int it = 0; it < 16; it++) {
            const int pr = w8 + it * 8;
            const float a0 = src[(size_t)(2 * pr) * HW];
            const float a1 = src[(size_t)(2 * pr + 1) * HW];
            dst[(size_t)pr * 64] = f2bf(a0) | (f2bf(a1) << 16);
        }
        return;
    }
    if (bx == 256 && t < 128) stats[t] = 0.f;
    const int i = (bx - 256) * 512 + t;                // over 589824
    if (i >= 72 * 256 * 32) return;
    const int cl = i & 31;
    const int o  = (i >> 5) & 255;
    const int ks = i >> 13;
    const int c  = ((ks & 7) << 5) | cl;
    const int kk = ks >> 3;
    wtb[i] = (ushort)f2bf(w[((size_t)o * Cin + c) * 9 + kk]);
}

// ---------------------------------------------------------------------------
// Kernel 2: fused deformable sampling + bf16 MFMA conv + GN partial stats.
// CHANGE vs prev:
//  - pair-plane bf16 window [row][pair][x] (4B pixel stride): gather banks
//    ~(x+dx)%32 -> <=2-way (the 16B-unit layout was a measured 8-way).
//  - grid 512 (half-row blocks, N=32): LDS 61.4KB -> 2 blocks/CU genuinely
//    resident (round 5 had grid=256, so co-residency never happened).
// Block: 512 threads (8 waves): N=32 px, M=256 Co.
// ---------------------------------------------------------------------------
__launch_bounds__(512, 4)
__global__ void dcn_kernel(const float* __restrict__ in,
                           const unsigned* __restrict__ inT,
                           const float* __restrict__ offs,
                           const float* __restrict__ mask,
                           const ushort* __restrict__ wtb,
                           const float* __restrict__ bias,
                           float* __restrict__ out,
                           float* __restrict__ stats) {
    extern __shared__ char smem[];
    ushort* col  = (ushort*)(smem + OFF_COL);   // [2][32*CSTR]
    int2*   s_ta = (int2*)(smem + OFF_TA);      // [288]
    float4* s_tw = (float4*)(smem + OFF_TW);    // [288]
    int*    s_ctl = (int*)(smem + OFF_CTL);     // [0]=ymin [1]=ymax

    const int t  = threadIdx.x;
    const int bx = blockIdx.x;
    // XCD swizzle: XCD q = bx&7 serves batch q>>1, h-half q&1 (L2 locality).
    const int q  = bx & 7, r = bx >> 3;
    const int b  = q >> 1;
    const int h  = ((q & 1) << 5) | (r >> 1);
    const int wb = (r & 1) << 5;           // x-half base: 0 or 32
    const int lane = t & 63;
    const int wv   = t >> 6;               // wave 0..7
    const int quad = lane >> 4;
    const int l15  = lane & 15;
    const int px   = lane & 31;            // pixel in half-row (gather role)
    const int hi   = lane >> 5;            // which channel-pair of the wave's 4ch
    const int proff = (2 * wv + hi) * 256; // pair-plane byte offset in window row

    if (t < 2) s_ctl[t] = (t == 0) ? 64 : -1;
    __syncthreads();

    // ---- tap precompute: 9 kernel points x 32 pixels, + block row min/max ----
    int my_min = 64, my_max = -1;
    for (int j = t; j < 288; j += 512) {
        const int k = j >> 5, p = j & 31;
        const int pp = wb + p;
        const float* ob = offs + (size_t)b * 18 * HW + h * Ww + pp;
        const float dy = ob[(2 * k) * HW];
        const float dx = ob[(2 * k + 1) * HW];
        const float m  = mask[((size_t)b * 9 + k) * HW + h * Ww + pp];
        const float y = (float)h + (float)(k / 3 - 1) + dy;
        const float x = (float)pp + (float)(k % 3 - 1) + dx;
        const float y0f = floorf(y), x0f = floorf(x);
        const float ly = y - y0f, lx = x - x0f;
        const float hy = 1.f - ly, hx = 1.f - lx;
        const int y0 = (int)y0f, x0 = (int)x0f;
        const int yc0 = min(max(y0, 0), 63);
        const int yc1 = min(max(y0 + 1, 0), 63);
        const int xb  = min(max(x0, 0), 62);
        // col-remapped pair coefficients (corner validity folded):
        //   v.x = col[xb], v.y = col[xb+1]
        float ax = 0.f, ay = 0.f;
        if (x0 == xb) {                       // x0 in [0,62]: both corners in-row
            ax = hx;
            ay = lx;
        } else if (x0 < xb) {                 // x0 < 0
            ax = (x0 + 1 == 0) ? lx : 0.f;
        } else {                              // x0 > 62
            ay = (x0 == 63) ? hx : 0.f;
        }
        const float w0 = (y0 >= 0 && y0 < 64) ? m * hy : 0.f;
        const float w1 = (y0 + 1 >= 0 && y0 + 1 < 64) ? m * ly : 0.f;
        // ta in staged-LDS byte units: row*ROWB + x*4 (u32 pixel words)
        s_ta[j] = make_int2(yc0 * ROWB + xb * 4, yc1 * ROWB + xb * 4);
        s_tw[j] = make_float4(w0 * ax, w0 * ay, w1 * ax, w1 * ay);
        my_min = min(my_min, yc0);
        my_max = max(my_max, yc1);
    }
#pragma unroll
    for (int off = 32; off; off >>= 1) {
        my_min = min(my_min, __shfl_xor(my_min, off));
        my_max = max(my_max, __shfl_xor(my_max, off));
    }
    if (lane == 0) {
        atomicMin(&s_ctl[0], my_min);
        atomicMax(&s_ctl[1], my_max);
    }
    __syncthreads();

    const int ymin = s_ctl[0];
    const bool use_lds = (s_ctl[1] - ymin + 1) <= SPAN;
    const int ybase = ymin * ROWB;

    f32x4 acc[2][2];
#pragma unroll
    for (int i = 0; i < 2; i++)
#pragma unroll
        for (int nt = 0; nt < 2; nt++) acc[i][nt] = (f32x4){0.f, 0.f, 0.f, 0.f};

    const float* inb = in + (size_t)b * Cin * HW;

    // Stage chunk cc: SPAN rows x 16 pair-planes x 64 px x 4B = 48 KB.
    // Per row: 16 planes contiguous in global (4 KB) = 4 linear 1KB segments.
#define STAGE(cc)                                                              \
    {                                                                          \
        _Pragma("unroll")                                                      \
        for (int i = 0; i < 6; i++) {                                          \
            const int g = wv * 6 + i;                                          \
            const int rr = g >> 2, seg = g & 3;                                \
            const int row = min(ymin + rr, 63);                                \
            const unsigned* src = inT +                                        \
                ((size_t)(b * 64 + row) * 128 + (cc) * 16) * 64 +              \
                seg * 256 + lane * 4;                                          \
            __builtin_amdgcn_global_load_lds(                                  \
                (const __attribute__((address_space(1))) void*)src,            \
                (__attribute__((address_space(3))) void*)(smem + OFF_IN +      \
                    rr * ROWB + seg * 1024),                                   \
                16, 0, 0);                                                     \
        }                                                                      \
    }

    // gather this thread's channel-pair for tap kk: one 8B load per corner row
    // (covers both x corners of the pair-plane)
#define GATHER_L(kk, pk)                                                   \
    {                                                                      \
        const int2  ad = s_ta[(kk) * 32 + px];                             \
        const float4 tw = s_tw[(kk) * 32 + px];                            \
        const char* bp = smem + OFF_IN + proff - ybase;                    \
        const float2 f0 = ld8((const float*)(bp + ad.x));                  \
        const float2 f1 = ld8((const float*)(bp + ad.y));                  \
        const unsigned u00 = __float_as_uint(f0.x);                        \
        const unsigned u01 = __float_as_uint(f0.y);                        \
        const unsigned u10 = __float_as_uint(f1.x);                        \
        const unsigned u11 = __float_as_uint(f1.y);                        \
        const float v0 = tw.x * BLO(u00) + tw.y * BLO(u01) +               \
                         tw.z * BLO(u10) + tw.w * BLO(u11);                \
        const float v1 = tw.x * BHI(u00) + tw.y * BHI(u01) +               \
                         tw.z * BHI(u10) + tw.w * BHI(u11);                \
        pk = f2bf(v0) | (f2bf(v1) << 16);                                  \
    }

    // fallback: gather from NCHW global f32 (span > SPAN; ~never taken)
#define GATHER_G(cc, kk, pk)                                               \
    {                                                                      \
        const int2  ad = s_ta[(kk) * 32 + px];                             \
        const float4 tw = s_tw[(kk) * 32 + px];                            \
        const int y0r = ad.x / ROWB, x0r = (ad.x - y0r * ROWB) >> 2;       \
        const int y1r = ad.y / ROWB, x1r = (ad.y - y1r * ROWB) >> 2;       \
        const int adx = y0r * 64 + x0r, ady = y1r * 64 + x1r;              \
        const float* cb = inb + (size_t)((cc) * 32 + wv * 4 + hi * 2) * HW;\
        float vv[2];                                                       \
        _Pragma("unroll")                                                  \
        for (int j = 0; j < 2; j++) {                                      \
            const float* pl = cb + j * HW;                                 \
            const float2 g0 = ld8(pl + adx);                               \
            const float2 g1 = ld8(pl + ady);                               \
            vv[j] = tw.x * g0.x + tw.y * g0.y + tw.z * g1.x + tw.w * g1.y; \
        }                                                                  \
        pk = f2bf(vv[0]) | (f2bf(vv[1]) << 16);                           \
    }

#define FRAGS_MFMA(ks, p)                                                      \
    {                                                                          \
        const ushort* wp =                                                     \
            wtb + ((size_t)((ks) * 256 + wv * 32 + l15)) * 32 + quad * 8;      \
        const short8 a0 = *(const short8*)wp;                                  \
        const short8 a1 = *(const short8*)(wp + 16 * 32);                      \
        short8 bfr[2];                                                         \
        _Pragma("unroll")                                                      \
        for (int nt = 0; nt < 2; nt++)                                         \
            bfr[nt] = *(const short8*)&col[(p) * (32 * CSTR) +                 \
                                           (nt * 16 + l15) * CSTR + quad * 8]; \
        _Pragma("unroll")                                                      \
        for (int nt = 0; nt < 2; nt++) {                                       \
            acc[0][nt] = __builtin_amdgcn_mfma_f32_16x16x32_bf16(              \
                a0, bfr[nt], acc[0][nt], 0, 0, 0);                             \
            acc[1][nt] = __builtin_amdgcn_mfma_f32_16x16x32_bf16(              \
                a1, bfr[nt], acc[1][nt], 0, 0, 0);                             \
        }                                                                      \
    }

    unsigned pk;
    int p = 0;

    if (use_lds) {
        STAGE(0);
        __syncthreads();                 // drains vmcnt: chunk 0 staged
        GATHER_L(0, pk);
#pragma unroll 1
        for (int s = 0; s < 72; s++) {
            const int cc = s / 9;
            const int kk = s - cc * 9;
            const int ks = kk * 8 + cc;
            *(unsigned*)&col[p * (32 * CSTR) + px * CSTR + (wv << 2) + (hi << 1)] = pk;
            __syncthreads();
            // all gathers of chunk cc done before this barrier -> safe to
            // overwrite the window with chunk cc+1.
            const bool bound = (kk == 8) && (s != 71);
            if (bound) {
                STAGE(cc + 1);           // async loads fly over the MFMAs
            } else if (s != 71) {
                GATHER_L(kk + 1, pk);
            }
            FRAGS_MFMA(ks, p);
            if (bound) {
                __syncthreads();         // staging complete (vmcnt drained)
                GATHER_L(0, pk);
            }
            p ^= 1;
        }
    } else {
        GATHER_G(0, 0, pk);
#pragma unroll 1
        for (int s = 0; s < 72; s++) {
            const int cc = s / 9;
            const int kk = s - cc * 9;
            const int ks = kk * 8 + cc;
            *(unsigned*)&col[p * (32 * CSTR) + px * CSTR + (wv << 2) + (hi << 1)] = pk;
            __syncthreads();
            if (s < 71) {
                const int s1 = s + 1;
                const int cc1 = s1 / 9;
                GATHER_G(cc1, s1 - cc1 * 9, pk);
            }
            FRAGS_MFMA(ks, p);
            p ^= 1;
        }
    }
#undef STAGE
#undef GATHER_L
#undef GATHER_G
#undef FRAGS_MFMA

    // ---- epilogue: bias, store, GN partial stats ----
    float gs[2], gq[2];
#pragma unroll
    for (int i = 0; i < 2; i++) {
        float s = 0.f, qq = 0.f;
        const int ob = wv * 32 + i * 16 + quad * 4;
#pragma unroll
        for (int reg = 0; reg < 4; reg++) {
            const int o = ob + reg;
            const float bv = bias[o];
            float* op = out + ((size_t)(b * 256 + o)) * HW + h * Ww + wb + l15;
#pragma unroll
            for (int nt = 0; nt < 2; nt++) {
                const float v = acc[i][nt][reg] + bv;
                op[nt * 16] = v;
                s += v;
                qq += v * v;
            }
        }
        gs[i] = s; gq[i] = qq;
    }
#pragma unroll
    for (int off = 32; off; off >>= 1) {
        gs[0] += __shfl_xor(gs[0], off);
        gq[0] += __shfl_xor(gq[0], off);
        gs[1] += __shfl_xor(gs[1], off);
        gq[1] += __shfl_xor(gq[1], off);
    }
    if (lane == 0) {
#pragma unroll
        for (int i = 0; i < 2; i++) {
            const int g = wv * 2 + i;
            atomicAdd(&stats[((size_t)b * NG + g) * 2],     gs[i]);
            atomicAdd(&stats[((size_t)b * NG + g) * 2 + 1], gq[i]);
        }
    }
}

// ---------------------------------------------------------------------------
// Kernel 3: GN apply (mu/rsqrt from accumulated sums, in place)
// ---------------------------------------------------------------------------
__global__ void gn_apply_kernel(float* __restrict__ x, const float* __restrict__ stats,
                                const float* __restrict__ gamma,
                                const float* __restrict__ beta) {
    const int i = blockIdx.x * 256 + threadIdx.x;      // float4 idx, 1048576 total
    const int plane = i >> 10;                         // b*256 + o
    const int o = plane & 255;
    const int bg = plane >> 4;                         // b*16 + g
    const float s = stats[bg * 2], q = stats[bg * 2 + 1];
    const float inv_n = 1.f / 65536.f;
    const float mu = s * inv_n;
    const float var = q * inv_n - mu * mu;
    const float rs = rsqrtf(var + EPSV);
    const float ga = gamma[o] * rs;
    const float be = beta[o] - mu * ga;
    float4 v = ((float4*)x)[i];
    v.x = v.x * ga + be;
    v.y = v.y * ga + be;
    v.z = v.z * ga + be;
    v.w = v.w * ga + be;
    ((float4*)x)[i] = v;
}

// ---------------------------------------------------------------------------
extern "C" void kernel_launch(void* const* d_in, const int* in_sizes, int n_in,
                              void* d_out, int out_size, void* d_ws, size_t ws_size,
                              hipStream_t stream) {
    const float* input  = (const float*)d_in[0];
    const float* offset = (const float*)d_in[1];
    const float* maskp  = (const float*)d_in[2];
    const float* weight = (const float*)d_in[3];
    const float* bias   = (const float*)d_in[4];
    const float* gamma  = (const float*)d_in[5];
    const float* beta   = (const float*)d_in[6];
    float* out = (float*)d_out;

    ushort* wtb  = (ushort*)d_ws;                           // 1.18 MB
    float* stats = (float*)((char*)d_ws + (size_t)Cout * Cin * 9 * sizeof(ushort));
    unsigned* inT = (unsigned*)((char*)d_ws + 1180160);     // 8 MB bf16 pair-plane

    static int attr_done = 0;
    if (!attr_done) {
        hipFuncSetAttribute((const void*)dcn_kernel,
                            hipFuncAttributeMaxDynamicSharedMemorySize, SMEM_BYTES);
        attr_done = 1;
    }

    hipLaunchKernelGGL(prep_kernel, dim3(256 + 1152), dim3(512), 0, stream,
                       input, weight, inT, wtb, stats);
    hipLaunchKernelGGL(dcn_kernel, dim3(Bsz * Hh * 2), dim3(512), SMEM_BYTES, stream,
                       input, inT, offset, maskp, wtb, bias, out, stats);
    hipLaunchKernelGGL(gn_apply_kernel, dim3((Bsz * Cout * HW / 4) / 256), dim3(256), 0,
                       stream, out, stats, gamma, beta);
}

// Round 7
// 194.357 us; speedup vs baseline: 1.0612x; 1.0612x over previous
//
#include <hip/hip_runtime.h>

typedef __attribute__((ext_vector_type(8))) short short8;   // 8 x bf16 (4 VGPR)
typedef __attribute__((ext_vector_type(4))) float f32x4;

#define Bsz 4
#define Cin 256
#define Cout 256
#define Hh 64
#define Ww 64
#define HW 4096
#define NG 16
#define EPSV 1e-5f

#define CSTR 40        // col LDS row stride in ushorts: 32 data + 8 pad = 80 B
#define SPAN 12        // staged input rows per window
#define ROWB 4112      // staged row stride bytes: 16 pairs x 64 px x 4B + 16 pad

// ---- dcn dynamic LDS layout (bytes) ----
#define OFF_IN   0
#define SZ_IN    (SPAN * ROWB)         // 49344: bf16 pair-plane window
#define OFF_COL  49344                 // 9 x 32 x CSTR ushorts = 23040 (9 taps)
#define OFF_TA   72384                 // int2 per tap [9][32] = 2304
#define OFF_TW   74688                 // float4 per tap [9][32] = 4608
#define OFF_CTL  79296                 // ymin/ymax
#define SMEM_BYTES 79312               // x2 blocks = 158624 <= 160 KiB/CU

static __device__ __forceinline__ unsigned f2bf(float f) {
    unsigned u = __float_as_uint(f);
    return (u + 0x7fffu + ((u >> 16) & 1u)) >> 16;   // RNE bf16
}

static __device__ __forceinline__ float2 ld8(const float* p) {
    float2 v;
    __builtin_memcpy(&v, p, 8);   // 8B load (global or LDS)
    return v;
}

#define BLO(u) __uint_as_float((u) << 16)          // bf16 in low half -> f32
#define BHI(u) __uint_as_float((u) & 0xffff0000u)  // bf16 in high half -> f32

// ---------------------------------------------------------------------------
// Kernel 1 (fused prep):
//  blocks [0,256): input transpose NCHW f32 -> bf16 pair-plane
//      inT word(u32 = ch2p lo | ch2p+1 hi) idx = ((b*64+y)*128 + pr)*64 + x
//  blocks [256,1408): weight reorder w[o][c][kk] -> bf16 wtb[ks][o][32],
//      ks = kk*8 + c/32;  + zero GN stats accumulators.
// ---------------------------------------------------------------------------
__launch_bounds__(512)
__global__ void prep_kernel(const float* __restrict__ in,
                            const float* __restrict__ w,
                            unsigned* __restrict__ inT,
                            ushort* __restrict__ wtb,
                            float* __restrict__ stats) {
    const int t  = threadIdx.x;
    const int bx = blockIdx.x;
    if (bx < 256) {                    // ---- transpose ----
        const int b = bx >> 6, y = bx & 63;
        const int x = t & 63, w8 = t >> 6;
        const float* src = in + (size_t)b * 256 * HW + y * 64 + x;
        unsigned* dst = inT + ((size_t)(b * 64 + y) * 128) * 64 + x;
#pragma unroll
        for (int it = 0; it < 16; it++) {
            const int pr = w8 + it * 8;
            const float a0 = src[(size_t)(2 * pr) * HW];
            const float a1 = src[(size_t)(2 * pr + 1) * HW];
            dst[(size_t)pr * 64] = f2bf(a0) | (f2bf(a1) << 16);
        }
        return;
    }
    if (bx == 256 && t < 128) stats[t] = 0.f;
    const int i = (bx - 256) * 512 + t;                // over 589824
    if (i >= 72 * 256 * 32) return;
    const int cl = i & 31;
    const int o  = (i >> 5) & 255;
    const int ks = i >> 13;
    const int c  = ((ks & 7) << 5) | cl;
    const int kk = ks >> 3;
    wtb[i] = (ushort)f2bf(w[((size_t)o * Cin + c) * 9 + kk]);
}

// ---------------------------------------------------------------------------
// Kernel 2: fused deformable sampling + bf16 MFMA conv + GN partial stats.
// CHANGE vs prev: per-step time was pinned at ~4k cycles across rounds 1-6
// with all pipes <20% busy -> the 72-iteration barrier-lockstep chain itself
// is the limiter. Restructured to BATCH ALL 9 TAPS per chunk:
//   gather phase (18 indep LDS loads, full ILP) -> barrier A -> async STAGE
//   of next chunk over a barrier-free 9x MFMA phase -> barrier B.
// Barriers per block: 144 -> 16. col holds all 9 taps (no double buffer).
// Block: 512 threads (8 waves): N=32 px, M=256 Co; grid 512 (2 blocks/CU).
// ---------------------------------------------------------------------------
__launch_bounds__(512, 4)
__global__ void dcn_kernel(const float* __restrict__ in,
                           const unsigned* __restrict__ inT,
                           const float* __restrict__ offs,
                           const float* __restrict__ mask,
                           const ushort* __restrict__ wtb,
                           const float* __restrict__ bias,
                           float* __restrict__ out,
                           float* __restrict__ stats) {
    extern __shared__ char smem[];
    ushort* col  = (ushort*)(smem + OFF_COL);   // [9][32*CSTR]
    int2*   s_ta = (int2*)(smem + OFF_TA);      // [288]
    float4* s_tw = (float4*)(smem + OFF_TW);    // [288]
    int*    s_ctl = (int*)(smem + OFF_CTL);     // [0]=ymin [1]=ymax

    const int t  = threadIdx.x;
    const int bx = blockIdx.x;
    // XCD swizzle: XCD q = bx&7 serves batch q>>1, h-half q&1 (L2 locality).
    const int q  = bx & 7, r = bx >> 3;
    const int b  = q >> 1;
    const int h  = ((q & 1) << 5) | (r >> 1);
    const int wb = (r & 1) << 5;           // x-half base: 0 or 32
    const int lane = t & 63;
    const int wv   = t >> 6;               // wave 0..7
    const int quad = lane >> 4;
    const int l15  = lane & 15;
    const int px   = lane & 31;            // pixel in half-row (gather role)
    const int hi   = lane >> 5;            // which channel-pair of the wave's 4ch
    const int proff = (2 * wv + hi) * 256; // pair-plane byte offset in window row

    if (t < 2) s_ctl[t] = (t == 0) ? 64 : -1;
    __syncthreads();

    // ---- tap precompute: 9 kernel points x 32 pixels, + block row min/max ----
    int my_min = 64, my_max = -1;
    for (int j = t; j < 288; j += 512) {
        const int k = j >> 5, p = j & 31;
        const int pp = wb + p;
        const float* ob = offs + (size_t)b * 18 * HW + h * Ww + pp;
        const float dy = ob[(2 * k) * HW];
        const float dx = ob[(2 * k + 1) * HW];
        const float m  = mask[((size_t)b * 9 + k) * HW + h * Ww + pp];
        const float y = (float)h + (float)(k / 3 - 1) + dy;
        const float x = (float)pp + (float)(k % 3 - 1) + dx;
        const float y0f = floorf(y), x0f = floorf(x);
        const float ly = y - y0f, lx = x - x0f;
        const float hy = 1.f - ly, hx = 1.f - lx;
        const int y0 = (int)y0f, x0 = (int)x0f;
        const int yc0 = min(max(y0, 0), 63);
        const int yc1 = min(max(y0 + 1, 0), 63);
        const int xb  = min(max(x0, 0), 62);
        // col-remapped pair coefficients (corner validity folded):
        //   v.x = col[xb], v.y = col[xb+1]
        float ax = 0.f, ay = 0.f;
        if (x0 == xb) {                       // x0 in [0,62]: both corners in-row
            ax = hx;
            ay = lx;
        } else if (x0 < xb) {                 // x0 < 0
            ax = (x0 + 1 == 0) ? lx : 0.f;
        } else {                              // x0 > 62
            ay = (x0 == 63) ? hx : 0.f;
        }
        const float w0 = (y0 >= 0 && y0 < 64) ? m * hy : 0.f;
        const float w1 = (y0 + 1 >= 0 && y0 + 1 < 64) ? m * ly : 0.f;
        // ta in staged-LDS byte units: row*ROWB + x*4 (u32 pixel words)
        s_ta[j] = make_int2(yc0 * ROWB + xb * 4, yc1 * ROWB + xb * 4);
        s_tw[j] = make_float4(w0 * ax, w0 * ay, w1 * ax, w1 * ay);
        my_min = min(my_min, yc0);
        my_max = max(my_max, yc1);
    }
#pragma unroll
    for (int off = 32; off; off >>= 1) {
        my_min = min(my_min, __shfl_xor(my_min, off));
        my_max = max(my_max, __shfl_xor(my_max, off));
    }
    if (lane == 0) {
        atomicMin(&s_ctl[0], my_min);
        atomicMax(&s_ctl[1], my_max);
    }
    __syncthreads();

    const int ymin = s_ctl[0];
    const bool use_lds = (s_ctl[1] - ymin + 1) <= SPAN;
    const int ybase = ymin * ROWB;

    f32x4 acc[2][2];
#pragma unroll
    for (int i = 0; i < 2; i++)
#pragma unroll
        for (int nt = 0; nt < 2; nt++) acc[i][nt] = (f32x4){0.f, 0.f, 0.f, 0.f};

    const float* inb = in + (size_t)b * Cin * HW;

    // Stage chunk cc: SPAN rows x 16 pair-planes x 64 px x 4B = 48 KB.
    // Per row: 16 planes contiguous in global (4 KB) = 4 linear 1KB segments.
#define STAGE(cc)                                                              \
    {                                                                          \
        _Pragma("unroll")                                                      \
        for (int i = 0; i < 6; i++) {                                          \
            const int g = wv * 6 + i;                                          \
            const int rr = g >> 2, seg = g & 3;                                \
            const int row = min(ymin + rr, 63);                                \
            const unsigned* src = inT +                                        \
                ((size_t)(b * 64 + row) * 128 + (cc) * 16) * 64 +              \
                seg * 256 + lane * 4;                                          \
            __builtin_amdgcn_global_load_lds(                                  \
                (const __attribute__((address_space(1))) void*)src,            \
                (__attribute__((address_space(3))) void*)(smem + OFF_IN +      \
                    rr * ROWB + seg * 1024),                                   \
                16, 0, 0);                                                     \
        }                                                                      \
    }

    // gather this thread's channel-pair for tap kk (window) and publish to col
#define GATHER_PUB_L(kk)                                                   \
    {                                                                      \
        const int2  ad = s_ta[(kk) * 32 + px];                             \
        const float4 tw = s_tw[(kk) * 32 + px];                            \
        const char* bp = smem + OFF_IN + proff - ybase;                    \
        const float2 f0 = ld8((const float*)(bp + ad.x));                  \
        const float2 f1 = ld8((const float*)(bp + ad.y));                  \
        const unsigned u00 = __float_as_uint(f0.x);                        \
        const unsigned u01 = __float_as_uint(f0.y);                        \
        const unsigned u10 = __float_as_uint(f1.x);                        \
        const unsigned u11 = __float_as_uint(f1.y);                        \
        const float v0 = tw.x * BLO(u00) + tw.y * BLO(u01) +               \
                         tw.z * BLO(u10) + tw.w * BLO(u11);                \
        const float v1 = tw.x * BHI(u00) + tw.y * BHI(u01) +               \
                         tw.z * BHI(u10) + tw.w * BHI(u11);                \
        *(unsigned*)&col[(kk) * (32 * CSTR) + px * CSTR + (wv << 2) +      \
                         (hi << 1)] = f2bf(v0) | (f2bf(v1) << 16);         \
    }

    // fallback: gather from NCHW global f32 (span > SPAN; ~never taken)
#define GATHER_PUB_G(cc, kk)                                               \
    {                                                                      \
        const int2  ad = s_ta[(kk) * 32 + px];                             \
        const float4 tw = s_tw[(kk) * 32 + px];                            \
        const int y0r = ad.x / ROWB, x0r = (ad.x - y0r * ROWB) >> 2;       \
        const int y1r = ad.y / ROWB, x1r = (ad.y - y1r * ROWB) >> 2;       \
        const int adx = y0r * 64 + x0r, ady = y1r * 64 + x1r;              \
        const float* cb = inb + (size_t)((cc) * 32 + wv * 4 + hi * 2) * HW;\
        float vv[2];                                                       \
        _Pragma("unroll")                                                  \
        for (int j = 0; j < 2; j++) {                                      \
            const float* pl = cb + j * HW;                                 \
            const float2 g0 = ld8(pl + adx);                               \
            const float2 g1 = ld8(pl + ady);                               \
            vv[j] = tw.x * g0.x + tw.y * g0.y + tw.z * g1.x + tw.w * g1.y; \
        }                                                                  \
        *(unsigned*)&col[(kk) * (32 * CSTR) + px * CSTR + (wv << 2) +      \
                         (hi << 1)] = f2bf(vv[0]) | (f2bf(vv[1]) << 16);   \
    }

#define FRAGS_MFMA(ks, kk)                                                     \
    {                                                                          \
        const ushort* wp =                                                     \
            wtb + ((size_t)((ks) * 256 + wv * 32 + l15)) * 32 + quad * 8;      \
        const short8 a0 = *(const short8*)wp;                                  \
        const short8 a1 = *(const short8*)(wp + 16 * 32);                      \
        short8 bfr[2];                                                         \
        _Pragma("unroll")                                                      \
        for (int nt = 0; nt < 2; nt++)                                         \
            bfr[nt] = *(const short8*)&col[(kk) * (32 * CSTR) +                \
                                           (nt * 16 + l15) * CSTR + quad * 8]; \
        _Pragma("unroll")                                                      \
        for (int nt = 0; nt < 2; nt++) {                                       \
            acc[0][nt] = __builtin_amdgcn_mfma_f32_16x16x32_bf16(              \
                a0, bfr[nt], acc[0][nt], 0, 0, 0);                             \
            acc[1][nt] = __builtin_amdgcn_mfma_f32_16x16x32_bf16(              \
                a1, bfr[nt], acc[1][nt], 0, 0, 0);                             \
        }                                                                      \
    }

    if (use_lds) {
        STAGE(0);
        __syncthreads();                 // window 0 staged (vmcnt drained)
#pragma unroll 1
        for (int cc = 0; cc < 8; cc++) {
            // ---- gather phase: all 9 taps, independent loads (ILP) ----
#pragma unroll 3
            for (int kk = 0; kk < 9; kk++) GATHER_PUB_L(kk);
            __syncthreads();             // A: col ready; window reads done
            if (cc < 7) STAGE(cc + 1);   // async overwrite of window
            // ---- MFMA phase: 9 taps, no barriers ----
#pragma unroll 3
            for (int kk = 0; kk < 9; kk++) FRAGS_MFMA(kk * 8 + cc, kk);
            __syncthreads();             // B: staging drained; col reads done
        }
    } else {
#pragma unroll 1
        for (int cc = 0; cc < 8; cc++) {
#pragma unroll 1
            for (int kk = 0; kk < 9; kk++) GATHER_PUB_G(cc, kk);
            __syncthreads();
#pragma unroll 3
            for (int kk = 0; kk < 9; kk++) FRAGS_MFMA(kk * 8 + cc, kk);
            __syncthreads();
        }
    }
#undef STAGE
#undef GATHER_PUB_L
#undef GATHER_PUB_G
#undef FRAGS_MFMA

    // ---- epilogue: bias, store, GN partial stats ----
    float gs[2], gq[2];
#pragma unroll
    for (int i = 0; i < 2; i++) {
        float s = 0.f, qq = 0.f;
        const int ob = wv * 32 + i * 16 + quad * 4;
#pragma unroll
        for (int reg = 0; reg < 4; reg++) {
            const int o = ob + reg;
            const float bv = bias[o];
            float* op = out + ((size_t)(b * 256 + o)) * HW + h * Ww + wb + l15;
#pragma unroll
            for (int nt = 0; nt < 2; nt++) {
                const float v = acc[i][nt][reg] + bv;
                op[nt * 16] = v;
                s += v;
                qq += v * v;
            }
        }
        gs[i] = s; gq[i] = qq;
    }
#pragma unroll
    for (int off = 32; off; off >>= 1) {
        gs[0] += __shfl_xor(gs[0], off);
        gq[0] += __shfl_xor(gq[0], off);
        gs[1] += __shfl_xor(gs[1], off);
        gq[1] += __shfl_xor(gq[1], off);
    }
    if (lane == 0) {
#pragma unroll
        for (int i = 0; i < 2; i++) {
            const int g = wv * 2 + i;
            atomicAdd(&stats[((size_t)b * NG + g) * 2],     gs[i]);
            atomicAdd(&stats[((size_t)b * NG + g) * 2 + 1], gq[i]);
        }
    }
}

// ---------------------------------------------------------------------------
// Kernel 3: GN apply (mu/rsqrt from accumulated sums, in place)
// ---------------------------------------------------------------------------
__global__ void gn_apply_kernel(float* __restrict__ x, const float* __restrict__ stats,
                                const float* __restrict__ gamma,
                                const float* __restrict__ beta) {
    const int i = blockIdx.x * 256 + threadIdx.x;      // float4 idx, 1048576 total
    const int plane = i >> 10;                         // b*256 + o
    const int o = plane & 255;
    const int bg = plane >> 4;                         // b*16 + g
    const float s = stats[bg * 2], q = stats[bg * 2 + 1];
    const float inv_n = 1.f / 65536.f;
    const float mu = s * inv_n;
    const float var = q * inv_n - mu * mu;
    const float rs = rsqrtf(var + EPSV);
    const float ga = gamma[o] * rs;
    const float be = beta[o] - mu * ga;
    float4 v = ((float4*)x)[i];
    v.x = v.x * ga + be;
    v.y = v.y * ga + be;
    v.z = v.z * ga + be;
    v.w = v.w * ga + be;
    ((float4*)x)[i] = v;
}

// ---------------------------------------------------------------------------
extern "C" void kernel_launch(void* const* d_in, const int* in_sizes, int n_in,
                              void* d_out, int out_size, void* d_ws, size_t ws_size,
                              hipStream_t stream) {
    const float* input  = (const float*)d_in[0];
    const float* offset = (const float*)d_in[1];
    const float* maskp  = (const float*)d_in[2];
    const float* weight = (const float*)d_in[3];
    const float* bias   = (const float*)d_in[4];
    const float* gamma  = (const float*)d_in[5];
    const float* beta   = (const float*)d_in[6];
    float* out = (float*)d_out;

    ushort* wtb  = (ushort*)d_ws;                           // 1.18 MB
    float* stats = (float*)((char*)d_ws + (size_t)Cout * Cin * 9 * sizeof(ushort));
    unsigned* inT = (unsigned*)((char*)d_ws + 1180160);     // 8 MB bf16 pair-plane

    static int attr_done = 0;
    if (!attr_done) {
        hipFuncSetAttribute((const void*)dcn_kernel,
                            hipFuncAttributeMaxDynamicSharedMemorySize, SMEM_BYTES);
        attr_done = 1;
    }

    hipLaunchKernelGGL(prep_kernel, dim3(256 + 1152), dim3(512), 0, stream,
                       input, weight, inT, wtb, stats);
    hipLaunchKernelGGL(dcn_kernel, dim3(Bsz * Hh * 2), dim3(512), SMEM_BYTES, stream,
                       input, inT, offset, maskp, wtb, bias, out, stats);
    hipLaunchKernelGGL(gn_apply_kernel, dim3((Bsz * Cout * HW / 4) / 256), dim3(256), 0,
                       stream, out, stats, gamma, beta);
}